// Round 1
// baseline (433.316 us; speedup 1.0000x reference)
//
#include <hip/hip_runtime.h>

// Problem: Sampler — pooled = mean over stride-2 grid of b, then 2 tiny FCs.
// Input a / attn_w / attn_b are dead (attn is DCE'd in the reference).
// b: [8,128,256,256] f32. Output: [8,128,1,1] f32 (1024 elems).

#define B_DIM 8
#define C_DIM 128
#define H_DIM 256
#define W_DIM 256
#define HWSZ  (H_DIM * W_DIM)      // 65536
#define NPLANE (B_DIM * C_DIM)     // 1024

// Kernel 1: per-plane reduction over even rows / even cols.
// One block per (b,c) plane. Each wave reads one full even row per iter
// as 64 coalesced float4 (1 KB), sums .x and .z (the even columns).
__global__ __launch_bounds__(256) void pool_kernel(const float* __restrict__ b,
                                                   float* __restrict__ pooled) {
    const int plane = blockIdx.x;                 // 0..1023
    const float* base = b + (size_t)plane * HWSZ;
    const int tid  = threadIdx.x;
    const int col4 = tid & 63;                    // float4 index within row (0..63)
    const int rq   = tid >> 6;                    // wave id 0..3

    float acc = 0.f;
    #pragma unroll
    for (int i = 0; i < 32; ++i) {
        const int er  = rq + 4 * i;               // even-row index 0..127
        const int row = er << 1;                  // actual row (even)
        float4 v = ((const float4*)(base + (size_t)row * W_DIM))[col4];
        acc += v.x + v.z;                         // even columns only
    }

    // wave (64-lane) tree reduce
    #pragma unroll
    for (int off = 32; off > 0; off >>= 1)
        acc += __shfl_down(acc, off, 64);

    __shared__ float ws[4];
    if ((tid & 63) == 0) ws[rq] = acc;
    __syncthreads();
    if (tid == 0)
        pooled[plane] = (ws[0] + ws[1] + ws[2] + ws[3]) * (1.0f / 65536.0f);
}

// Kernel 2: hidden = relu(pooled @ fc1^T) ; out = hidden @ fc2^T.
// One block of 256 threads; everything staged in LDS with +1 padding to
// avoid same-bank serialization (row stride 128/32 -> all lanes one bank).
__global__ __launch_bounds__(256) void fc_kernel(const float* __restrict__ pooled,
                                                 const float* __restrict__ fc1_w,  // [32,128]
                                                 const float* __restrict__ fc2_w,  // [128,32]
                                                 float* __restrict__ out) {        // [8,128]
    __shared__ float s_pooled[B_DIM * C_DIM];     // 1024
    __shared__ float s_fc1[32 * 129];             // padded rows
    __shared__ float s_fc2[128 * 33];             // padded rows
    __shared__ float s_hidden[B_DIM * 32];        // 256

    const int tid = threadIdx.x;
    for (int i = tid; i < 1024; i += 256) s_pooled[i] = pooled[i];
    for (int i = tid; i < 4096; i += 256) {
        int j = i >> 7, c = i & 127;
        s_fc1[j * 129 + c] = fc1_w[i];
    }
    for (int i = tid; i < 4096; i += 256) {
        int o = i >> 5, j = i & 31;
        s_fc2[o * 33 + j] = fc2_w[i];
    }
    __syncthreads();

    // hidden[b][j]: 256 outputs, one per thread
    {
        const int bb = tid >> 5, j = tid & 31;
        const float* p = s_pooled + bb * C_DIM;
        const float* w = s_fc1 + j * 129;
        float h = 0.f;
        #pragma unroll
        for (int c = 0; c < C_DIM; ++c) h += p[c] * w[c];
        s_hidden[tid] = h > 0.f ? h : 0.f;
    }
    __syncthreads();

    // out[b][o]: 1024 outputs, 4 per thread
    for (int idx = tid; idx < 1024; idx += 256) {
        const int bb = idx >> 7, o = idx & 127;
        const float* h = s_hidden + bb * 32;
        const float* w = s_fc2 + o * 33;
        float a = 0.f;
        #pragma unroll
        for (int j = 0; j < 32; ++j) a += h[j] * w[j];
        out[idx] = a;
    }
}

extern "C" void kernel_launch(void* const* d_in, const int* in_sizes, int n_in,
                              void* d_out, int out_size, void* d_ws, size_t ws_size,
                              hipStream_t stream) {
    const float* b     = (const float*)d_in[1];
    const float* fc1_w = (const float*)d_in[4];
    const float* fc2_w = (const float*)d_in[5];
    float* out    = (float*)d_out;
    float* pooled = (float*)d_ws;                 // 1024 floats of scratch

    pool_kernel<<<NPLANE, 256, 0, stream>>>(b, pooled);
    fc_kernel<<<1, 256, 0, stream>>>(pooled, fc1_w, fc2_w, out);
}